// Round 1
// baseline (1829.493 us; speedup 1.0000x reference)
//
#include <hip/hip_runtime.h>
#include <cstddef>

#define BB 8
#define TT 128
#define NN 256
#define DD 64

typedef _Float16 half2_t __attribute__((ext_vector_type(2)));

#if defined(__has_builtin)
#  if __has_builtin(__builtin_amdgcn_fdot2)
#    define FDOT2(a,b,c) __builtin_amdgcn_fdot2((a),(b),(c),false)
#  endif
#endif
#ifndef FDOT2
#  define FDOT2(a,b,c) ((c) + (float)(a).x*(float)(b).x + (float)(a).y*(float)(b).y)
#endif

// ---------------- K1: fused QKV + per-(b,n) temporal attention ----------------
__global__ __launch_bounds__(128) void k_attn(
    const float* __restrict__ Hi, const float* __restrict__ Hj,
    const float* __restrict__ Wq, const float* __restrict__ bq,
    const float* __restrict__ Wk, const float* __restrict__ bk,
    const float* __restrict__ Wv, const float* __restrict__ bv,
    const float* __restrict__ lg, const float* __restrict__ lt,
    float* __restrict__ out)
{
  __shared__ float sK[TT][DD];   // 32KB
  __shared__ float sV[TT][DD];   // 32KB
  const int b = blockIdx.x >> 8;
  const int n = blockIdx.x & 255;
  const int i = threadIdx.x;     // row 0..127

  const float gamma = fmaxf(__expf(lg[0]), 0.01f);
  const float tau   = fmaxf(__expf(lt[0]), 0.01f);
  const float scale = 1.0f / (8.0f * tau);
  const float ginv  = gamma * (1.0f / 127.0f);

  // stage Hj[b,:,n,:] into sV (coalesced)
  const float* HjB = Hj + ((size_t)b * TT * NN + n) * DD;
  for (int idx = i; idx < TT * DD; idx += 128) {
    int t = idx >> 6, d = idx & 63;
    sV[t][d] = HjB[(size_t)t * NN * DD + d];
  }
  __syncthreads();

  // own Hj row -> regs
  float hj[DD];
  {
    const float4* r = (const float4*)sV[i];
    #pragma unroll
    for (int dq = 0; dq < 16; dq++) {
      float4 v = r[dq];
      hj[4*dq] = v.x; hj[4*dq+1] = v.y; hj[4*dq+2] = v.z; hj[4*dq+3] = v.w;
    }
  }
  // K row -> sK[i]
  {
    float4* kw = (float4*)sK[i];
    for (int eq = 0; eq < 16; eq++) {
      float s0 = bk[4*eq], s1 = bk[4*eq+1], s2 = bk[4*eq+2], s3 = bk[4*eq+3];
      const float4* w0 = (const float4*)(Wk + (4*eq)   * DD);
      const float4* w1 = (const float4*)(Wk + (4*eq+1) * DD);
      const float4* w2 = (const float4*)(Wk + (4*eq+2) * DD);
      const float4* w3 = (const float4*)(Wk + (4*eq+3) * DD);
      #pragma unroll
      for (int dq = 0; dq < 16; dq++) {
        float4 a = w0[dq], bb2 = w1[dq], c = w2[dq], d4 = w3[dq];
        float h0 = hj[4*dq], h1 = hj[4*dq+1], h2 = hj[4*dq+2], h3 = hj[4*dq+3];
        s0 += h0*a.x + h1*a.y + h2*a.z + h3*a.w;
        s1 += h0*bb2.x + h1*bb2.y + h2*bb2.z + h3*bb2.w;
        s2 += h0*c.x + h1*c.y + h2*c.z + h3*c.w;
        s3 += h0*d4.x + h1*d4.y + h2*d4.z + h3*d4.w;
      }
      kw[eq] = make_float4(s0, s1, s2, s3);
    }
  }
  // V row -> sV[i]  (safe: every thread only touches its own row, already copied)
  {
    float4* vw = (float4*)sV[i];
    for (int eq = 0; eq < 16; eq++) {
      float s0 = bv[4*eq], s1 = bv[4*eq+1], s2 = bv[4*eq+2], s3 = bv[4*eq+3];
      const float4* w0 = (const float4*)(Wv + (4*eq)   * DD);
      const float4* w1 = (const float4*)(Wv + (4*eq+1) * DD);
      const float4* w2 = (const float4*)(Wv + (4*eq+2) * DD);
      const float4* w3 = (const float4*)(Wv + (4*eq+3) * DD);
      #pragma unroll
      for (int dq = 0; dq < 16; dq++) {
        float4 a = w0[dq], bb2 = w1[dq], c = w2[dq], d4 = w3[dq];
        float h0 = hj[4*dq], h1 = hj[4*dq+1], h2 = hj[4*dq+2], h3 = hj[4*dq+3];
        s0 += h0*a.x + h1*a.y + h2*a.z + h3*a.w;
        s1 += h0*bb2.x + h1*bb2.y + h2*bb2.z + h3*bb2.w;
        s2 += h0*c.x + h1*c.y + h2*c.z + h3*c.w;
        s3 += h0*d4.x + h1*d4.y + h2*d4.z + h3*d4.w;
      }
      vw[eq] = make_float4(s0, s1, s2, s3);
    }
  }
  // Q row -> regs
  float q[DD];
  {
    float hi_[DD];
    const float4* hr = (const float4*)(Hi + (((size_t)b * TT + i) * NN + n) * DD);
    #pragma unroll
    for (int dq = 0; dq < 16; dq++) {
      float4 v = hr[dq];
      hi_[4*dq] = v.x; hi_[4*dq+1] = v.y; hi_[4*dq+2] = v.z; hi_[4*dq+3] = v.w;
    }
    #pragma unroll
    for (int e = 0; e < DD; e++) {
      float s = bq[e];
      const float4* w = (const float4*)(Wq + e * DD);
      #pragma unroll
      for (int dq = 0; dq < 16; dq++) {
        float4 wv = w[dq];
        s += hi_[4*dq]*wv.x + hi_[4*dq+1]*wv.y + hi_[4*dq+2]*wv.z + hi_[4*dq+3]*wv.w;
      }
      q[e] = s;
    }
  }
  __syncthreads();

  // online-softmax attention over j
  float m = -1e30f, l = 0.0f;
  float acc[DD];
  #pragma unroll
  for (int d = 0; d < DD; d++) acc[d] = 0.0f;

  for (int j = 0; j < TT; j++) {
    const float4* kr = (const float4*)sK[j];
    float s = 0.0f;
    #pragma unroll
    for (int dq = 0; dq < 16; dq++) {
      float4 kv = kr[dq];
      s += q[4*dq]*kv.x + q[4*dq+1]*kv.y + q[4*dq+2]*kv.z + q[4*dq+3]*kv.w;
    }
    float dt = fabsf((float)(i - j)) * ginv;
    s = s * scale + logf(__expf(-dt) + 1e-8f);
    float mn = fmaxf(m, s);
    float al = __expf(m - mn);
    float p  = __expf(s - mn);
    l = l * al + p;
    const float4* vr = (const float4*)sV[j];
    #pragma unroll
    for (int dq = 0; dq < 16; dq++) {
      float4 vv = vr[dq];
      acc[4*dq]   = acc[4*dq]  *al + p*vv.x;
      acc[4*dq+1] = acc[4*dq+1]*al + p*vv.y;
      acc[4*dq+2] = acc[4*dq+2]*al + p*vv.z;
      acc[4*dq+3] = acc[4*dq+3]*al + p*vv.w;
    }
    m = mn;
  }
  float rl = 1.0f / l;
  float4* o4 = (float4*)(out + (((size_t)b * TT + i) * NN + n) * DD);
  #pragma unroll
  for (int dq = 0; dq < 16; dq++)
    o4[dq] = make_float4(acc[4*dq]*rl, acc[4*dq+1]*rl, acc[4*dq+2]*rl, acc[4*dq+3]*rl);
}

// ---------------- K2: adjacency adpT[n][m] = softmax_row_m(relu(e1@e2)) ----------------
__global__ __launch_bounds__(256) void k_adp(
    const float* __restrict__ e1, const float* __restrict__ e2,
    float* __restrict__ adpT)
{
  const int m = blockIdx.x, n = threadIdx.x;
  float s = 0.f;
  #pragma unroll
  for (int k = 0; k < 32; k++) s += e1[m*32+k] * e2[k*256+n];
  s = fmaxf(s, 0.f);
  __shared__ float red[256];
  red[n] = s; __syncthreads();
  for (int off = 128; off > 0; off >>= 1) {
    if (n < off) red[n] = fmaxf(red[n], red[n+off]);
    __syncthreads();
  }
  float mx = red[0];
  __syncthreads();
  float p = __expf(s - mx);
  red[n] = p; __syncthreads();
  for (int off = 128; off > 0; off >>= 1) {
    if (n < off) red[n] += red[n+off];
    __syncthreads();
  }
  adpT[n*256 + m] = p / red[0];
}

// ---------------- K3: GCN + residual + LN1 (in-place on x) ----------------
__global__ __launch_bounds__(256) void k_gcn(
    float* __restrict__ x, const float* __restrict__ adpT,
    const float* __restrict__ Wg, const float* __restrict__ bg,
    const float* __restrict__ g1, const float* __restrict__ b1)
{
  __shared__ float sx[NN][DD];  // 64KB
  float* tile = x + (size_t)blockIdx.x * NN * DD;
  for (int idx = threadIdx.x; idx < NN * DD; idx += 256)
    sx[idx >> 6][idx & 63] = tile[idx];
  __syncthreads();

  const int m = threadIdx.x;
  float g[DD];
  #pragma unroll
  for (int d = 0; d < DD; d++) g[d] = 0.f;
  for (int n = 0; n < NN; n++) {
    float a = adpT[n * 256 + m];
    const float4* r = (const float4*)sx[n];
    #pragma unroll
    for (int dq = 0; dq < 16; dq++) {
      float4 v = r[dq];
      g[4*dq]   += a * v.x; g[4*dq+1] += a * v.y;
      g[4*dq+2] += a * v.z; g[4*dq+3] += a * v.w;
    }
  }
  float y[DD]; float s1 = 0.f;
  #pragma unroll
  for (int e = 0; e < DD; e++) {
    float h = bg[e];
    const float4* w = (const float4*)(Wg + e * DD);
    #pragma unroll
    for (int dq = 0; dq < 16; dq++) {
      float4 wv = w[dq];
      h += g[4*dq]*wv.x + g[4*dq+1]*wv.y + g[4*dq+2]*wv.z + g[4*dq+3]*wv.w;
    }
    h = fmaxf(h, 0.f);
    float yv = sx[m][e] + h;
    y[e] = yv; s1 += yv;
  }
  float mean = s1 * (1.f/64.f);
  float s2 = 0.f;
  #pragma unroll
  for (int e = 0; e < DD; e++) { float d0 = y[e] - mean; s2 += d0 * d0; }
  float rstd = rsqrtf(s2 * (1.f/64.f) + 1e-5f);
  float* orow = tile + m * DD;
  #pragma unroll
  for (int e = 0; e < DD; e++) orow[e] = (y[e] - mean) * rstd * g1[e] + b1[e];
}

// ---------------- K4: GRU over T + LN2 + final residual (in-place on x) ----------------
__global__ __launch_bounds__(256) void k_gru(
    float* __restrict__ x,
    const float* __restrict__ Wih, const float* __restrict__ Whh,
    const float* __restrict__ bih, const float* __restrict__ bhh,
    const float* __restrict__ g2, const float* __restrict__ b2)
{
  __shared__ half2_t sWi[192][33];  // fp16 weights, pad-33 half2 -> conflict-free
  __shared__ half2_t sWh[192][33];
  __shared__ float   xs[4][64];
  __shared__ half2_t xs_h[4][32];
  __shared__ float   hs_f[4][64];
  __shared__ half2_t hs_h[4][32];
  __shared__ float   gis[4][192];
  __shared__ float   ghs[4][192];

  const int b  = blockIdx.x >> 6;
  const int ng = blockIdx.x & 63;

  for (int idx = threadIdx.x; idx < 192 * 32; idx += 256) {
    int g = idx >> 5, dh = idx & 31;
    half2_t hv; hv.x = (_Float16)Wih[g*64 + 2*dh]; hv.y = (_Float16)Wih[g*64 + 2*dh + 1];
    sWi[g][dh] = hv;
    half2_t hw; hw.x = (_Float16)Whh[g*64 + 2*dh]; hw.y = (_Float16)Whh[g*64 + 2*dh + 1];
    sWh[g][dh] = hw;
  }
  const int s_d = threadIdx.x >> 6;
  const int d_d = threadIdx.x & 63;
  hs_f[s_d][d_d] = 0.f;
  ((_Float16*)hs_h[s_d])[d_d] = (_Float16)0.f;
  const float lng = g2[d_d], lnb = b2[d_d];

  int   tsk_s[3], tsk_g[3];
  float tb_i[3], tb_h[3];
  #pragma unroll
  for (int k = 0; k < 3; k++) {
    int task = threadIdx.x + k * 256;
    tsk_s[k] = task / 192; tsk_g[k] = task % 192;
    tb_i[k] = bih[tsk_g[k]]; tb_h[k] = bhh[tsk_g[k]];
  }
  __syncthreads();

  const size_t base = (((size_t)b * TT) * NN + ng * 4) * DD;
  for (int t = 0; t < TT; t++) {
    const size_t row = base + (size_t)t * NN * DD + s_d * 64 + d_d;
    float xv = x[row];
    xs[s_d][d_d] = xv;
    ((_Float16*)xs_h[s_d])[d_d] = (_Float16)xv;
    __syncthreads();

    #pragma unroll
    for (int k = 0; k < 3; k++) {
      int s = tsk_s[k], g = tsk_g[k];
      float ai = tb_i[k], ah = tb_h[k];
      #pragma unroll
      for (int dh = 0; dh < 32; dh++) {
        ai = FDOT2(sWi[g][dh], xs_h[s][dh], ai);
        ah = FDOT2(sWh[g][dh], hs_h[s][dh], ah);
      }
      gis[s][g] = ai; ghs[s][g] = ah;
    }
    __syncthreads();

    float gr = gis[s_d][d_d]      + ghs[s_d][d_d];
    float gz = gis[s_d][64 + d_d] + ghs[s_d][64 + d_d];
    float r  = 1.f / (1.f + __expf(-gr));
    float z  = 1.f / (1.f + __expf(-gz));
    float nn = tanhf(gis[s_d][128 + d_d] + r * ghs[s_d][128 + d_d]);
    float ho = hs_f[s_d][d_d];
    float hn = (1.f - z) * nn + z * ho;

    float yv = xs[s_d][d_d] + hn;
    float s1 = yv, s2 = yv * yv;
    #pragma unroll
    for (int off = 32; off > 0; off >>= 1) {
      s1 += __shfl_xor(s1, off, 64);
      s2 += __shfl_xor(s2, off, 64);
    }
    float mean = s1 * (1.f / 64.f);
    float var  = fmaxf(s2 * (1.f / 64.f) - mean * mean, 0.f);
    float hm = (yv - mean) * rsqrtf(var + 1e-5f) * lng + lnb;

    x[row] = xs[s_d][d_d] + hm;
    hs_f[s_d][d_d] = hn;
    ((_Float16*)hs_h[s_d])[d_d] = (_Float16)hn;
    __syncthreads();
  }
}

extern "C" void kernel_launch(void* const* d_in, const int* in_sizes, int n_in,
                              void* d_out, int out_size, void* d_ws, size_t ws_size,
                              hipStream_t stream) {
  const float* Hi  = (const float*)d_in[0];
  const float* Hj  = (const float*)d_in[1];
  const float* Wq  = (const float*)d_in[2];  const float* bq = (const float*)d_in[3];
  const float* Wk  = (const float*)d_in[4];  const float* bk = (const float*)d_in[5];
  const float* Wv  = (const float*)d_in[6];  const float* bv = (const float*)d_in[7];
  const float* lg  = (const float*)d_in[8];  const float* lt = (const float*)d_in[9];
  const float* e1  = (const float*)d_in[10]; const float* e2 = (const float*)d_in[11];
  const float* Wg  = (const float*)d_in[12]; const float* bg = (const float*)d_in[13];
  const float* g1  = (const float*)d_in[14]; const float* b1 = (const float*)d_in[15];
  const float* Wih = (const float*)d_in[16]; const float* Whh = (const float*)d_in[17];
  const float* bih = (const float*)d_in[18]; const float* bhh = (const float*)d_in[19];
  const float* g2  = (const float*)d_in[20]; const float* b2  = (const float*)d_in[21];
  float* out  = (float*)d_out;
  float* adpT = (float*)d_ws;   // 256x256 floats = 256KB

  k_attn<<<dim3(BB*NN), dim3(128), 0, stream>>>(Hi, Hj, Wq, bq, Wk, bk, Wv, bv, lg, lt, out);
  k_adp <<<dim3(NN),    dim3(256), 0, stream>>>(e1, e2, adpT);
  k_gcn <<<dim3(BB*TT), dim3(256), 0, stream>>>(out, adpT, Wg, bg, g1, b1);
  k_gru <<<dim3(512),   dim3(256), 0, stream>>>(out, Wih, Whh, bih, bhh, g2, b2);
}

// Round 2
// 1198.607 us; speedup vs baseline: 1.5263x; 1.5263x over previous
//
#include <hip/hip_runtime.h>
#include <cstddef>

#define BB 8
#define TT 128
#define NN 256
#define DD 64

typedef _Float16 half2_t __attribute__((ext_vector_type(2)));

#if defined(__has_builtin)
#  if __has_builtin(__builtin_amdgcn_fdot2)
#    define FDOT2(a,b,c) __builtin_amdgcn_fdot2((a),(b),(c),false)
#  endif
#endif
#ifndef FDOT2
#  define FDOT2(a,b,c) ((c) + (float)(a).x*(float)(b).x + (float)(a).y*(float)(b).y)
#endif

// ---------------- K0: pack W matrices to half2 in ws (L2-resident, uniform s_loads later) ----
__global__ __launch_bounds__(256) void k_prep(
    const float* __restrict__ Wq, const float* __restrict__ Wk, const float* __restrict__ Wv,
    unsigned int* __restrict__ wq2, unsigned int* __restrict__ wk2, unsigned int* __restrict__ wv2)
{
  int t = blockIdx.x * 256 + threadIdx.x;
  if (t < 2048) {
    half2_t a; a.x = (_Float16)Wq[2*t]; a.y = (_Float16)Wq[2*t+1];
    wq2[t] = __builtin_bit_cast(unsigned int, a);
    half2_t b; b.x = (_Float16)Wk[2*t]; b.y = (_Float16)Wk[2*t+1];
    wk2[t] = __builtin_bit_cast(unsigned int, b);
    half2_t c; c.x = (_Float16)Wv[2*t]; c.y = (_Float16)Wv[2*t+1];
    wv2[t] = __builtin_bit_cast(unsigned int, c);
  }
}

// project one 64-row (half2[32]) against W (half2-packed, row-major [64][32]) + bias,
// write 64 fp16 outputs (scaled by mul) to dst (LDS). Weight/bias reads are wave-uniform.
__device__ __forceinline__ void proj_row_to(const half2_t* __restrict__ hh,
                                            const unsigned int* __restrict__ W2,
                                            const float* __restrict__ bias,
                                            half2_t* dst, float mul)
{
  #pragma unroll 4
  for (int e2 = 0; e2 < 32; e2++) {
    float a0 = bias[2*e2], a1 = bias[2*e2+1];
    const unsigned int* w0 = W2 + (2*e2) * 32;
    const unsigned int* w1 = w0 + 32;
    #pragma unroll
    for (int k = 0; k < 32; k++) {
      half2_t wa = __builtin_bit_cast(half2_t, w0[k]);
      half2_t wb = __builtin_bit_cast(half2_t, w1[k]);
      a0 = FDOT2(wa, hh[k], a0);
      a1 = FDOT2(wb, hh[k], a1);
    }
    half2_t o; o.x = (_Float16)(a0 * mul); o.y = (_Float16)(a1 * mul);
    dst[e2] = o;
  }
}

// ---------------- K1: fused QKV + per-(b,n) temporal attention (fp16 storage / fp32 acc) ----
__global__ __launch_bounds__(128, 3) void k_attn(
    const float* __restrict__ Hi, const float* __restrict__ Hj,
    const unsigned int* __restrict__ wq2, const unsigned int* __restrict__ wk2,
    const unsigned int* __restrict__ wv2,
    const float* __restrict__ bq, const float* __restrict__ bk, const float* __restrict__ bv,
    const float* __restrict__ lg, const float* __restrict__ lt,
    float* __restrict__ out)
{
  __shared__ half2_t sK[TT][DD/2];  // 16KB
  __shared__ half2_t sV[TT][DD/2];  // 16KB
  const int b = blockIdx.x >> 8;
  const int n = blockIdx.x & 255;
  const int i = threadIdx.x;        // row 0..127

  const float gamma = fmaxf(__expf(lg[0]), 0.01f);
  const float tau   = fmaxf(__expf(lt[0]), 0.01f);
  const float scale = 1.0f / (8.0f * tau);
  const float ginv  = gamma * (1.0f / 127.0f);

  half2_t hh[32];

  // ---- Q: load Hi row, project (scale folded in), park in sK[i], pull to regs ----
  {
    const float4* hr = (const float4*)(Hi + (((size_t)b * TT + i) * NN + n) * DD);
    #pragma unroll
    for (int dq = 0; dq < 16; dq++) {
      float4 v = hr[dq];
      half2_t a; a.x = (_Float16)v.x; a.y = (_Float16)v.y;
      half2_t c; c.x = (_Float16)v.z; c.y = (_Float16)v.w;
      hh[2*dq] = a; hh[2*dq+1] = c;
    }
  }
  proj_row_to(hh, wq2, bq, sK[i], scale);
  half2_t qh[32];
  #pragma unroll
  for (int k = 0; k < 32; k++) qh[k] = sK[i][k];  // own row only -> no barrier needed

  // ---- K,V: load Hj row, project into LDS ----
  {
    const float4* hr = (const float4*)(Hj + (((size_t)b * TT + i) * NN + n) * DD);
    #pragma unroll
    for (int dq = 0; dq < 16; dq++) {
      float4 v = hr[dq];
      half2_t a; a.x = (_Float16)v.x; a.y = (_Float16)v.y;
      half2_t c; c.x = (_Float16)v.z; c.y = (_Float16)v.w;
      hh[2*dq] = a; hh[2*dq+1] = c;
    }
  }
  proj_row_to(hh, wk2, bk, sK[i], 1.0f);
  proj_row_to(hh, wv2, bv, sV[i], 1.0f);
  __syncthreads();

  // ---- single-pass softmax-attention over j (no running max: scores bounded) ----
  float l = 0.0f;
  float acc[DD];
  #pragma unroll
  for (int d = 0; d < DD; d++) acc[d] = 0.0f;

  for (int j = 0; j < TT; j++) {
    const half2_t* kr = sK[j];   // broadcast reads: conflict-free
    float d0 = 0.f, d1 = 0.f, d2 = 0.f, d3 = 0.f;
    #pragma unroll
    for (int k = 0; k < 8; k++) {
      d0 = FDOT2(qh[k],      kr[k],      d0);
      d1 = FDOT2(qh[k + 8],  kr[k + 8],  d1);
      d2 = FDOT2(qh[k + 16], kr[k + 16], d2);
      d3 = FDOT2(qh[k + 24], kr[k + 24], d3);
    }
    float dt = fabsf((float)(i - j)) * ginv;
    float s  = (d0 + d1) + (d2 + d3) + __logf(__expf(-dt) + 1e-8f);
    float p  = __expf(s);
    l += p;
    const half2_t* vr = sV[j];
    #pragma unroll
    for (int k = 0; k < 32; k++) {
      half2_t v = vr[k];
      acc[2*k]     += p * (float)v.x;   // v_fma_mix
      acc[2*k + 1] += p * (float)v.y;
    }
  }
  float rl = 1.0f / l;
  float4* o4 = (float4*)(out + (((size_t)b * TT + i) * NN + n) * DD);
  #pragma unroll
  for (int dq = 0; dq < 16; dq++)
    o4[dq] = make_float4(acc[4*dq]*rl, acc[4*dq+1]*rl, acc[4*dq+2]*rl, acc[4*dq+3]*rl);
}

// ---------------- K2: adjacency adpT[n][m] = softmax_row_m(relu(e1@e2)) ----------------
__global__ __launch_bounds__(256) void k_adp(
    const float* __restrict__ e1, const float* __restrict__ e2,
    float* __restrict__ adpT)
{
  const int m = blockIdx.x, n = threadIdx.x;
  float s = 0.f;
  #pragma unroll
  for (int k = 0; k < 32; k++) s += e1[m*32+k] * e2[k*256+n];
  s = fmaxf(s, 0.f);
  __shared__ float red[256];
  red[n] = s; __syncthreads();
  for (int off = 128; off > 0; off >>= 1) {
    if (n < off) red[n] = fmaxf(red[n], red[n+off]);
    __syncthreads();
  }
  float mx = red[0];
  __syncthreads();
  float p = __expf(s - mx);
  red[n] = p; __syncthreads();
  for (int off = 128; off > 0; off >>= 1) {
    if (n < off) red[n] += red[n+off];
    __syncthreads();
  }
  adpT[n*256 + m] = p / red[0];
}

// ---------------- K3: GCN + residual + LN1 (in-place on x) ----------------
__global__ __launch_bounds__(256) void k_gcn(
    float* __restrict__ x, const float* __restrict__ adpT,
    const float* __restrict__ Wg, const float* __restrict__ bg,
    const float* __restrict__ g1, const float* __restrict__ b1)
{
  __shared__ float sx[NN][DD];  // 64KB
  float* tile = x + (size_t)blockIdx.x * NN * DD;
  for (int idx = threadIdx.x; idx < NN * DD; idx += 256)
    sx[idx >> 6][idx & 63] = tile[idx];
  __syncthreads();

  const int m = threadIdx.x;
  float g[DD];
  #pragma unroll
  for (int d = 0; d < DD; d++) g[d] = 0.f;
  for (int n = 0; n < NN; n++) {
    float a = adpT[n * 256 + m];
    const float4* r = (const float4*)sx[n];
    #pragma unroll
    for (int dq = 0; dq < 16; dq++) {
      float4 v = r[dq];
      g[4*dq]   += a * v.x; g[4*dq+1] += a * v.y;
      g[4*dq+2] += a * v.z; g[4*dq+3] += a * v.w;
    }
  }
  float y[DD]; float s1 = 0.f;
  #pragma unroll
  for (int e = 0; e < DD; e++) {
    float h = bg[e];
    const float4* w = (const float4*)(Wg + e * DD);
    #pragma unroll
    for (int dq = 0; dq < 16; dq++) {
      float4 wv = w[dq];
      h += g[4*dq]*wv.x + g[4*dq+1]*wv.y + g[4*dq+2]*wv.z + g[4*dq+3]*wv.w;
    }
    h = fmaxf(h, 0.f);
    float yv = sx[m][e] + h;
    y[e] = yv; s1 += yv;
  }
  float mean = s1 * (1.f/64.f);
  float s2 = 0.f;
  #pragma unroll
  for (int e = 0; e < DD; e++) { float d0 = y[e] - mean; s2 += d0 * d0; }
  float rstd = rsqrtf(s2 * (1.f/64.f) + 1e-5f);
  float* orow = tile + m * DD;
  #pragma unroll
  for (int e = 0; e < DD; e++) orow[e] = (y[e] - mean) * rstd * g1[e] + b1[e];
}

// ---------------- K4: GRU over T + LN2 + final residual (in-place on x) ----------------
__global__ __launch_bounds__(256) void k_gru(
    float* __restrict__ x,
    const float* __restrict__ Wih, const float* __restrict__ Whh,
    const float* __restrict__ bih, const float* __restrict__ bhh,
    const float* __restrict__ g2, const float* __restrict__ b2)
{
  __shared__ half2_t sWi[192][33];  // fp16 weights, pad-33 half2 -> conflict-free
  __shared__ half2_t sWh[192][33];
  __shared__ float   xs[4][64];
  __shared__ half2_t xs_h[4][32];
  __shared__ float   hs_f[4][64];
  __shared__ half2_t hs_h[4][32];
  __shared__ float   gis[4][192];
  __shared__ float   ghs[4][192];

  const int b  = blockIdx.x >> 6;
  const int ng = blockIdx.x & 63;

  for (int idx = threadIdx.x; idx < 192 * 32; idx += 256) {
    int g = idx >> 5, dh = idx & 31;
    half2_t hv; hv.x = (_Float16)Wih[g*64 + 2*dh]; hv.y = (_Float16)Wih[g*64 + 2*dh + 1];
    sWi[g][dh] = hv;
    half2_t hw; hw.x = (_Float16)Whh[g*64 + 2*dh]; hw.y = (_Float16)Whh[g*64 + 2*dh + 1];
    sWh[g][dh] = hw;
  }
  const int s_d = threadIdx.x >> 6;
  const int d_d = threadIdx.x & 63;
  hs_f[s_d][d_d] = 0.f;
  ((_Float16*)hs_h[s_d])[d_d] = (_Float16)0.f;
  const float lng = g2[d_d], lnb = b2[d_d];

  int   tsk_s[3], tsk_g[3];
  float tb_i[3], tb_h[3];
  #pragma unroll
  for (int k = 0; k < 3; k++) {
    int task = threadIdx.x + k * 256;
    tsk_s[k] = task / 192; tsk_g[k] = task % 192;
    tb_i[k] = bih[tsk_g[k]]; tb_h[k] = bhh[tsk_g[k]];
  }
  __syncthreads();

  const size_t base = (((size_t)b * TT) * NN + ng * 4) * DD;
  for (int t = 0; t < TT; t++) {
    const size_t row = base + (size_t)t * NN * DD + s_d * 64 + d_d;
    float xv = x[row];
    xs[s_d][d_d] = xv;
    ((_Float16*)xs_h[s_d])[d_d] = (_Float16)xv;
    __syncthreads();

    #pragma unroll
    for (int k = 0; k < 3; k++) {
      int s = tsk_s[k], g = tsk_g[k];
      float ai = tb_i[k], ah = tb_h[k];
      #pragma unroll
      for (int dh = 0; dh < 32; dh++) {
        ai = FDOT2(sWi[g][dh], xs_h[s][dh], ai);
        ah = FDOT2(sWh[g][dh], hs_h[s][dh], ah);
      }
      gis[s][g] = ai; ghs[s][g] = ah;
    }
    __syncthreads();

    float gr = gis[s_d][d_d]      + ghs[s_d][d_d];
    float gz = gis[s_d][64 + d_d] + ghs[s_d][64 + d_d];
    float r  = 1.f / (1.f + __expf(-gr));
    float z  = 1.f / (1.f + __expf(-gz));
    float nn = tanhf(gis[s_d][128 + d_d] + r * ghs[s_d][128 + d_d]);
    float ho = hs_f[s_d][d_d];
    float hn = (1.f - z) * nn + z * ho;

    float yv = xs[s_d][d_d] + hn;
    float s1 = yv, s2 = yv * yv;
    #pragma unroll
    for (int off = 32; off > 0; off >>= 1) {
      s1 += __shfl_xor(s1, off, 64);
      s2 += __shfl_xor(s2, off, 64);
    }
    float mean = s1 * (1.f / 64.f);
    float var  = fmaxf(s2 * (1.f / 64.f) - mean * mean, 0.f);
    float hm = (yv - mean) * rsqrtf(var + 1e-5f) * lng + lnb;

    x[row] = xs[s_d][d_d] + hm;
    hs_f[s_d][d_d] = hn;
    ((_Float16*)hs_h[s_d])[d_d] = (_Float16)hn;
    __syncthreads();
  }
}

extern "C" void kernel_launch(void* const* d_in, const int* in_sizes, int n_in,
                              void* d_out, int out_size, void* d_ws, size_t ws_size,
                              hipStream_t stream) {
  const float* Hi  = (const float*)d_in[0];
  const float* Hj  = (const float*)d_in[1];
  const float* Wq  = (const float*)d_in[2];  const float* bq = (const float*)d_in[3];
  const float* Wk  = (const float*)d_in[4];  const float* bk = (const float*)d_in[5];
  const float* Wv  = (const float*)d_in[6];  const float* bv = (const float*)d_in[7];
  const float* lg  = (const float*)d_in[8];  const float* lt = (const float*)d_in[9];
  const float* e1  = (const float*)d_in[10]; const float* e2 = (const float*)d_in[11];
  const float* Wg  = (const float*)d_in[12]; const float* bg = (const float*)d_in[13];
  const float* g1  = (const float*)d_in[14]; const float* b1 = (const float*)d_in[15];
  const float* Wih = (const float*)d_in[16]; const float* Whh = (const float*)d_in[17];
  const float* bih = (const float*)d_in[18]; const float* bhh = (const float*)d_in[19];
  const float* g2  = (const float*)d_in[20]; const float* b2  = (const float*)d_in[21];
  float* out  = (float*)d_out;

  float* adpT = (float*)d_ws;                          // 256x256 floats = 256KB
  unsigned int* wq2 = (unsigned int*)d_ws + 65536;     // 2048 u32 each
  unsigned int* wk2 = wq2 + 2048;
  unsigned int* wv2 = wk2 + 2048;

  k_prep<<<dim3(8),     dim3(256), 0, stream>>>(Wq, Wk, Wv, wq2, wk2, wv2);
  k_attn<<<dim3(BB*NN), dim3(128), 0, stream>>>(Hi, Hj, wq2, wk2, wv2, bq, bk, bv, lg, lt, out);
  k_adp <<<dim3(NN),    dim3(256), 0, stream>>>(e1, e2, adpT);
  k_gcn <<<dim3(BB*TT), dim3(256), 0, stream>>>(out, adpT, Wg, bg, g1, b1);
  k_gru <<<dim3(512),   dim3(256), 0, stream>>>(out, Wih, Whh, bih, bhh, g2, b2);
}

// Round 3
// 1046.525 us; speedup vs baseline: 1.7482x; 1.1453x over previous
//
#include <hip/hip_runtime.h>
#include <cstddef>

#define BB 8
#define TT 128
#define NN 256
#define DD 64

typedef _Float16 half2_t __attribute__((ext_vector_type(2)));
typedef _Float16 half8_t __attribute__((ext_vector_type(8)));

#if defined(__has_builtin)
#  if __has_builtin(__builtin_amdgcn_fdot2)
#    define FDOT2(a,b,c) __builtin_amdgcn_fdot2((a),(b),(c),false)
#  endif
#endif
#ifndef FDOT2
#  define FDOT2(a,b,c) ((c) + (float)(a).x*(float)(b).x + (float)(a).y*(float)(b).y)
#endif

union h8u { half8_t v; half2_t h[4]; };

// ---------------- K0: pack W matrices to half2 in ws ----------------
__global__ __launch_bounds__(256) void k_prep(
    const float* __restrict__ Wq, const float* __restrict__ Wk, const float* __restrict__ Wv,
    unsigned int* __restrict__ wq2, unsigned int* __restrict__ wk2, unsigned int* __restrict__ wv2)
{
  int t = blockIdx.x * 256 + threadIdx.x;
  if (t < 2048) {
    half2_t a; a.x = (_Float16)Wq[2*t]; a.y = (_Float16)Wq[2*t+1];
    wq2[t] = __builtin_bit_cast(unsigned int, a);
    half2_t b; b.x = (_Float16)Wk[2*t]; b.y = (_Float16)Wk[2*t+1];
    wk2[t] = __builtin_bit_cast(unsigned int, b);
    half2_t c; c.x = (_Float16)Wv[2*t]; c.y = (_Float16)Wv[2*t+1];
    wv2[t] = __builtin_bit_cast(unsigned int, c);
  }
}

__device__ __forceinline__ void proj_row_to(const half2_t* __restrict__ hh,
                                            const unsigned int* __restrict__ W2,
                                            const float* __restrict__ bias,
                                            half2_t* dst, float mul)
{
  #pragma unroll 4
  for (int e2 = 0; e2 < 32; e2++) {
    float a0 = bias[2*e2], a1 = bias[2*e2+1];
    const unsigned int* w0 = W2 + (2*e2) * 32;
    const unsigned int* w1 = w0 + 32;
    #pragma unroll
    for (int k = 0; k < 32; k++) {
      half2_t wa = __builtin_bit_cast(half2_t, w0[k]);
      half2_t wb = __builtin_bit_cast(half2_t, w1[k]);
      a0 = FDOT2(wa, hh[k], a0);
      a1 = FDOT2(wb, hh[k], a1);
    }
    half2_t o; o.x = (_Float16)(a0 * mul); o.y = (_Float16)(a1 * mul);
    dst[e2] = o;
  }
}

// ---------------- K1: fused QKV + per-(b,n) temporal attention ----------------
__global__ __launch_bounds__(128, 3) void k_attn(
    const float* __restrict__ Hi, const float* __restrict__ Hj,
    const unsigned int* __restrict__ wq2, const unsigned int* __restrict__ wk2,
    const unsigned int* __restrict__ wv2,
    const float* __restrict__ bq, const float* __restrict__ bk, const float* __restrict__ bv,
    const float* __restrict__ lg, const float* __restrict__ lt,
    float* __restrict__ out)
{
  __shared__ half2_t sK[TT][DD/2];  // 16KB
  __shared__ half2_t sV[TT][DD/2];  // 16KB
  const int b = blockIdx.x >> 8;
  const int n = blockIdx.x & 255;
  const int i = threadIdx.x;

  const float gamma = fmaxf(__expf(lg[0]), 0.01f);
  const float tau   = fmaxf(__expf(lt[0]), 0.01f);
  const float scale = 1.0f / (8.0f * tau);
  const float ginv  = gamma * (1.0f / 127.0f);

  half2_t hh[32];
  {
    const float4* hr = (const float4*)(Hi + (((size_t)b * TT + i) * NN + n) * DD);
    #pragma unroll
    for (int dq = 0; dq < 16; dq++) {
      float4 v = hr[dq];
      half2_t a; a.x = (_Float16)v.x; a.y = (_Float16)v.y;
      half2_t c; c.x = (_Float16)v.z; c.y = (_Float16)v.w;
      hh[2*dq] = a; hh[2*dq+1] = c;
    }
  }
  proj_row_to(hh, wq2, bq, sK[i], scale);
  half2_t qh[32];
  #pragma unroll
  for (int k = 0; k < 32; k++) qh[k] = sK[i][k];

  {
    const float4* hr = (const float4*)(Hj + (((size_t)b * TT + i) * NN + n) * DD);
    #pragma unroll
    for (int dq = 0; dq < 16; dq++) {
      float4 v = hr[dq];
      half2_t a; a.x = (_Float16)v.x; a.y = (_Float16)v.y;
      half2_t c; c.x = (_Float16)v.z; c.y = (_Float16)v.w;
      hh[2*dq] = a; hh[2*dq+1] = c;
    }
  }
  proj_row_to(hh, wk2, bk, sK[i], 1.0f);
  proj_row_to(hh, wv2, bv, sV[i], 1.0f);
  __syncthreads();

  float l = 0.0f;
  float acc[DD];
  #pragma unroll
  for (int d = 0; d < DD; d++) acc[d] = 0.0f;

  for (int j = 0; j < TT; j++) {
    const half2_t* kr = sK[j];
    float d0 = 0.f, d1 = 0.f, d2 = 0.f, d3 = 0.f;
    #pragma unroll
    for (int k = 0; k < 8; k++) {
      d0 = FDOT2(qh[k],      kr[k],      d0);
      d1 = FDOT2(qh[k + 8],  kr[k + 8],  d1);
      d2 = FDOT2(qh[k + 16], kr[k + 16], d2);
      d3 = FDOT2(qh[k + 24], kr[k + 24], d3);
    }
    float dt = fabsf((float)(i - j)) * ginv;
    float s  = (d0 + d1) + (d2 + d3) + __logf(__expf(-dt) + 1e-8f);
    float p  = __expf(s);
    l += p;
    const half2_t* vr = sV[j];
    #pragma unroll
    for (int k = 0; k < 32; k++) {
      half2_t v = vr[k];
      acc[2*k]     += p * (float)v.x;
      acc[2*k + 1] += p * (float)v.y;
    }
  }
  float rl = 1.0f / l;
  float4* o4 = (float4*)(out + (((size_t)b * TT + i) * NN + n) * DD);
  #pragma unroll
  for (int dq = 0; dq < 16; dq++)
    o4[dq] = make_float4(acc[4*dq]*rl, acc[4*dq+1]*rl, acc[4*dq+2]*rl, acc[4*dq+3]*rl);
}

// ---------------- K2: adjacency adpT[n][m] = softmax_row_m(relu(e1@e2)) ----------------
__global__ __launch_bounds__(256) void k_adp(
    const float* __restrict__ e1, const float* __restrict__ e2,
    float* __restrict__ adpT)
{
  const int m = blockIdx.x, n = threadIdx.x;
  float s = 0.f;
  #pragma unroll
  for (int k = 0; k < 32; k++) s += e1[m*32+k] * e2[k*256+n];
  s = fmaxf(s, 0.f);
  __shared__ float red[256];
  red[n] = s; __syncthreads();
  for (int off = 128; off > 0; off >>= 1) {
    if (n < off) red[n] = fmaxf(red[n], red[n+off]);
    __syncthreads();
  }
  float mx = red[0];
  __syncthreads();
  float p = __expf(s - mx);
  red[n] = p; __syncthreads();
  for (int off = 128; off > 0; off >>= 1) {
    if (n < off) red[n] += red[n+off];
    __syncthreads();
  }
  adpT[n*256 + m] = p / red[0];
}

// ---------------- K3: GCN + residual + LN1 (in-place on x) ----------------
__global__ __launch_bounds__(256) void k_gcn(
    float* __restrict__ x, const float* __restrict__ adpT,
    const float* __restrict__ Wg, const float* __restrict__ bg,
    const float* __restrict__ g1, const float* __restrict__ b1)
{
  __shared__ float sx[NN][DD];  // 64KB
  float* tile = x + (size_t)blockIdx.x * NN * DD;
  for (int idx = threadIdx.x; idx < NN * DD; idx += 256)
    sx[idx >> 6][idx & 63] = tile[idx];
  __syncthreads();

  const int m = threadIdx.x;
  float g[DD];
  #pragma unroll
  for (int d = 0; d < DD; d++) g[d] = 0.f;
  for (int n = 0; n < NN; n++) {
    float a = adpT[n * 256 + m];
    const float4* r = (const float4*)sx[n];
    #pragma unroll
    for (int dq = 0; dq < 16; dq++) {
      float4 v = r[dq];
      g[4*dq]   += a * v.x; g[4*dq+1] += a * v.y;
      g[4*dq+2] += a * v.z; g[4*dq+3] += a * v.w;
    }
  }
  float y[DD]; float s1 = 0.f;
  #pragma unroll
  for (int e = 0; e < DD; e++) {
    float h = bg[e];
    const float4* w = (const float4*)(Wg + e * DD);
    #pragma unroll
    for (int dq = 0; dq < 16; dq++) {
      float4 wv = w[dq];
      h += g[4*dq]*wv.x + g[4*dq+1]*wv.y + g[4*dq+2]*wv.z + g[4*dq+3]*wv.w;
    }
    h = fmaxf(h, 0.f);
    float yv = sx[m][e] + h;
    y[e] = yv; s1 += yv;
  }
  float mean = s1 * (1.f/64.f);
  float s2 = 0.f;
  #pragma unroll
  for (int e = 0; e < DD; e++) { float d0 = y[e] - mean; s2 += d0 * d0; }
  float rstd = rsqrtf(s2 * (1.f/64.f) + 1e-5f);
  float* orow = tile + m * DD;
  #pragma unroll
  for (int e = 0; e < DD; e++) orow[e] = (y[e] - mean) * rstd * g1[e] + b1[e];
}

// ---------------- K3b: GI[t][seq][192] = x_ln1 @ Wih^T + bih  (fp16, parallel) ----------
__global__ __launch_bounds__(256) void k_gih(
    const float* __restrict__ x, const float* __restrict__ Wih,
    const float* __restrict__ bih, unsigned int* __restrict__ GI2)
{
  __shared__ unsigned int sW[192*32];   // 24KB packed half2 weights
  __shared__ unsigned int sbuf[256*33]; // overlay: x-stage [256][33], then out-stage [256][25]
  const int tid = threadIdx.x;
  const int b = blockIdx.x >> 7, t = blockIdx.x & 127;
  const float* xt = x + (((size_t)b * TT + t) * NN) * DD;

  for (int idx = tid; idx < 192*32; idx += 256) {
    float2 w = ((const float2*)Wih)[idx];
    half2_t h; h.x = (_Float16)w.x; h.y = (_Float16)w.y;
    sW[idx] = __builtin_bit_cast(unsigned int, h);
  }
  for (int idx = tid; idx < 256*32; idx += 256) {
    int n = idx >> 5, k = idx & 31;
    float2 v = ((const float2*)xt)[idx];
    half2_t h; h.x = (_Float16)v.x; h.y = (_Float16)v.y;
    sbuf[n*33 + k] = __builtin_bit_cast(unsigned int, h);
  }
  __syncthreads();
  half2_t xr[32];
  #pragma unroll
  for (int k = 0; k < 32; k++) xr[k] = __builtin_bit_cast(half2_t, sbuf[tid*33 + k]);
  __syncthreads();

  const size_t blockbase = ((size_t)t * 2048 + b * 256) * 96;  // dword index
  for (int c = 0; c < 4; c++) {
    #pragma unroll 2
    for (int j2 = 0; j2 < 24; j2++) {
      int e0 = c*48 + 2*j2;
      float a0 = bih[e0], a1 = bih[e0+1];
      const half8_t* w0 = (const half8_t*)(sW + e0*32);
      const half8_t* w1 = (const half8_t*)(sW + (e0+1)*32);
      #pragma unroll
      for (int kq = 0; kq < 8; kq++) {
        h8u ua, ub; ua.v = w0[kq]; ub.v = w1[kq];
        #pragma unroll
        for (int m = 0; m < 4; m++) {
          a0 = FDOT2(ua.h[m], xr[4*kq+m], a0);
          a1 = FDOT2(ub.h[m], xr[4*kq+m], a1);
        }
      }
      half2_t o; o.x = (_Float16)a0; o.y = (_Float16)a1;
      sbuf[tid*25 + j2] = __builtin_bit_cast(unsigned int, o);
    }
    __syncthreads();
    for (int idx = tid; idx < 6144; idx += 256) {
      int n = idx / 24, e2 = idx % 24;
      GI2[blockbase + (size_t)n*96 + c*24 + e2] = sbuf[n*25 + e2];
    }
    __syncthreads();
  }
}

// ---------------- K4: GRU over T (gi precomputed) + LN2 + residual ----------------
__global__ __launch_bounds__(256) void k_gru_gi(
    float* __restrict__ x, const _Float16* __restrict__ GIh,
    const float* __restrict__ Whh, const float* __restrict__ bhh,
    const float* __restrict__ g2, const float* __restrict__ b2)
{
  __shared__ __align__(16) _Float16 hsh[4*64];
  __shared__ float ghs[4*192];
  const int tid = threadIdx.x;
  const int b = blockIdx.x >> 6, n4 = blockIdx.x & 63;
  const int s = tid >> 6, d = tid & 63;

  half2_t wh[32];
  float bh = 0.f;
  if (tid < 192) {
    bh = bhh[tid];
    const float2* wr = (const float2*)Whh;
    #pragma unroll
    for (int k = 0; k < 32; k++) {
      float2 w = wr[tid*32 + k];
      half2_t h; h.x = (_Float16)w.x; h.y = (_Float16)w.y;
      wh[k] = h;
    }
  }
  hsh[tid] = (_Float16)0.f;
  const float lng = g2[d], lnb = b2[d];
  float hreg = 0.f;
  size_t gioff = ((size_t)b*256 + n4*4 + s)*192 + d;
  size_t xoff  = (((size_t)b * TT) * NN + n4*4 + s)*DD + d;
  __syncthreads();

  for (int t = 0; t < TT; t++) {
    float gir = (float)GIh[gioff];
    float giz = (float)GIh[gioff + 64];
    float gin = (float)GIh[gioff + 128];
    float xv  = x[xoff];

    if (tid < 192) {
      float a0 = bh, a1 = bh, a2 = bh, a3 = bh;
      const half8_t* h8 = (const half8_t*)hsh;
      #pragma unroll
      for (int kq = 0; kq < 8; kq++) {
        h8u u0, u1, u2, u3;
        u0.v = h8[kq]; u1.v = h8[8+kq]; u2.v = h8[16+kq]; u3.v = h8[24+kq];
        #pragma unroll
        for (int m = 0; m < 4; m++) {
          half2_t w = wh[4*kq + m];
          a0 = FDOT2(w, u0.h[m], a0);
          a1 = FDOT2(w, u1.h[m], a1);
          a2 = FDOT2(w, u2.h[m], a2);
          a3 = FDOT2(w, u3.h[m], a3);
        }
      }
      ghs[tid] = a0; ghs[192 + tid] = a1; ghs[384 + tid] = a2; ghs[576 + tid] = a3;
    }
    __syncthreads();

    float rr = gir + ghs[s*192 + d];
    float zz = giz + ghs[s*192 + 64 + d];
    float hn_ = ghs[s*192 + 128 + d];
    float r = 1.f / (1.f + __expf(-rr));
    float z = 1.f / (1.f + __expf(-zz));
    float e = __expf(2.f * (gin + r * hn_));
    float nt = 1.f - 2.f / (e + 1.f);     // tanh, overflow-safe
    float hn = (1.f - z) * nt + z * hreg;
    hreg = hn;

    float yv = xv + hn;
    float s1 = yv, s2v = yv * yv;
    #pragma unroll
    for (int off = 32; off > 0; off >>= 1) {
      s1  += __shfl_xor(s1,  off, 64);
      s2v += __shfl_xor(s2v, off, 64);
    }
    float mean = s1 * 0.015625f;
    float var  = fmaxf(s2v * 0.015625f - mean * mean, 0.f);
    float hm = (yv - mean) * rsqrtf(var + 1e-5f) * lng + lnb;

    x[xoff] = xv + hm;
    hsh[tid] = (_Float16)hn;
    __syncthreads();

    gioff += (size_t)2048 * 192;
    xoff  += (size_t)NN * DD;
  }
}

// ---------------- K4 fallback: original fused GRU (ws too small for GI) ----------------
__global__ __launch_bounds__(256) void k_gru(
    float* __restrict__ x,
    const float* __restrict__ Wih, const float* __restrict__ Whh,
    const float* __restrict__ bih, const float* __restrict__ bhh,
    const float* __restrict__ g2, const float* __restrict__ b2)
{
  __shared__ half2_t sWi[192][33];
  __shared__ half2_t sWh[192][33];
  __shared__ float   xs[4][64];
  __shared__ half2_t xs_h[4][32];
  __shared__ float   hs_f[4][64];
  __shared__ half2_t hs_h[4][32];
  __shared__ float   gis[4][192];
  __shared__ float   ghs[4][192];

  const int b  = blockIdx.x >> 6;
  const int ng = blockIdx.x & 63;

  for (int idx = threadIdx.x; idx < 192 * 32; idx += 256) {
    int g = idx >> 5, dh = idx & 31;
    half2_t hv; hv.x = (_Float16)Wih[g*64 + 2*dh]; hv.y = (_Float16)Wih[g*64 + 2*dh + 1];
    sWi[g][dh] = hv;
    half2_t hw; hw.x = (_Float16)Whh[g*64 + 2*dh]; hw.y = (_Float16)Whh[g*64 + 2*dh + 1];
    sWh[g][dh] = hw;
  }
  const int s_d = threadIdx.x >> 6;
  const int d_d = threadIdx.x & 63;
  hs_f[s_d][d_d] = 0.f;
  ((_Float16*)hs_h[s_d])[d_d] = (_Float16)0.f;
  const float lng = g2[d_d], lnb = b2[d_d];

  int   tsk_s[3], tsk_g[3];
  float tb_i[3], tb_h[3];
  #pragma unroll
  for (int k = 0; k < 3; k++) {
    int task = threadIdx.x + k * 256;
    tsk_s[k] = task / 192; tsk_g[k] = task % 192;
    tb_i[k] = bih[tsk_g[k]]; tb_h[k] = bhh[tsk_g[k]];
  }
  __syncthreads();

  const size_t base = (((size_t)b * TT) * NN + ng * 4) * DD;
  for (int t = 0; t < TT; t++) {
    const size_t row = base + (size_t)t * NN * DD + s_d * 64 + d_d;
    float xv = x[row];
    xs[s_d][d_d] = xv;
    ((_Float16*)xs_h[s_d])[d_d] = (_Float16)xv;
    __syncthreads();

    #pragma unroll
    for (int k = 0; k < 3; k++) {
      int s = tsk_s[k], g = tsk_g[k];
      float ai = tb_i[k], ah = tb_h[k];
      #pragma unroll
      for (int dh = 0; dh < 32; dh++) {
        ai = FDOT2(sWi[g][dh], xs_h[s][dh], ai);
        ah = FDOT2(sWh[g][dh], hs_h[s][dh], ah);
      }
      gis[s][g] = ai; ghs[s][g] = ah;
    }
    __syncthreads();

    float gr = gis[s_d][d_d]      + ghs[s_d][d_d];
    float gz = gis[s_d][64 + d_d] + ghs[s_d][64 + d_d];
    float r  = 1.f / (1.f + __expf(-gr));
    float z  = 1.f / (1.f + __expf(-gz));
    float nn = tanhf(gis[s_d][128 + d_d] + r * ghs[s_d][128 + d_d]);
    float ho = hs_f[s_d][d_d];
    float hn = (1.f - z) * nn + z * ho;

    float yv = xs[s_d][d_d] + hn;
    float s1 = yv, s2 = yv * yv;
    #pragma unroll
    for (int off = 32; off > 0; off >>= 1) {
      s1 += __shfl_xor(s1, off, 64);
      s2 += __shfl_xor(s2, off, 64);
    }
    float mean = s1 * (1.f / 64.f);
    float var  = fmaxf(s2 * (1.f / 64.f) - mean * mean, 0.f);
    float hm = (yv - mean) * rsqrtf(var + 1e-5f) * lng + lnb;

    x[row] = xs[s_d][d_d] + hm;
    hs_f[s_d][d_d] = hn;
    ((_Float16*)hs_h[s_d])[d_d] = (_Float16)hn;
    __syncthreads();
  }
}

extern "C" void kernel_launch(void* const* d_in, const int* in_sizes, int n_in,
                              void* d_out, int out_size, void* d_ws, size_t ws_size,
                              hipStream_t stream) {
  const float* Hi  = (const float*)d_in[0];
  const float* Hj  = (const float*)d_in[1];
  const float* Wq  = (const float*)d_in[2];  const float* bq = (const float*)d_in[3];
  const float* Wk  = (const float*)d_in[4];  const float* bk = (const float*)d_in[5];
  const float* Wv  = (const float*)d_in[6];  const float* bv = (const float*)d_in[7];
  const float* lg  = (const float*)d_in[8];  const float* lt = (const float*)d_in[9];
  const float* e1  = (const float*)d_in[10]; const float* e2 = (const float*)d_in[11];
  const float* Wg  = (const float*)d_in[12]; const float* bg = (const float*)d_in[13];
  const float* g1  = (const float*)d_in[14]; const float* b1 = (const float*)d_in[15];
  const float* Wih = (const float*)d_in[16]; const float* Whh = (const float*)d_in[17];
  const float* bih = (const float*)d_in[18]; const float* bhh = (const float*)d_in[19];
  const float* g2  = (const float*)d_in[20]; const float* b2  = (const float*)d_in[21];
  float* out  = (float*)d_out;

  float* adpT = (float*)d_ws;                          // 256KB @ offset 0
  unsigned int* wq2 = (unsigned int*)d_ws + 65536;     // 3 x 8KB
  unsigned int* wk2 = wq2 + 2048;
  unsigned int* wv2 = wk2 + 2048;
  const size_t gi_off = 286720;                        // byte offset, 512-aligned
  const size_t gi_bytes = (size_t)2048 * TT * 192 * 2; // 96MB fp16
  const bool use_gi = ws_size >= gi_off + gi_bytes;
  unsigned int* GI2 = (unsigned int*)((char*)d_ws + gi_off);
  _Float16*     GIh = (_Float16*)((char*)d_ws + gi_off);

  k_prep<<<dim3(8),     dim3(256), 0, stream>>>(Wq, Wk, Wv, wq2, wk2, wv2);
  k_attn<<<dim3(BB*NN), dim3(128), 0, stream>>>(Hi, Hj, wq2, wk2, wv2, bq, bk, bv, lg, lt, out);
  k_adp <<<dim3(NN),    dim3(256), 0, stream>>>(e1, e2, adpT);
  k_gcn <<<dim3(BB*TT), dim3(256), 0, stream>>>(out, adpT, Wg, bg, g1, b1);
  if (use_gi) {
    k_gih   <<<dim3(BB*TT), dim3(256), 0, stream>>>(out, Wih, bih, GI2);
    k_gru_gi<<<dim3(512),   dim3(256), 0, stream>>>(out, GIh, Whh, bhh, g2, b2);
  } else {
    k_gru   <<<dim3(512),   dim3(256), 0, stream>>>(out, Wih, Whh, bih, bhh, g2, b2);
  }
}